// Round 1
// baseline (561.011 us; speedup 1.0000x reference)
//
#include <hip/hip_runtime.h>
#include <hip/hip_bf16.h>

#define NN 100000
#define NE 50000
#define NT 2000
#define DD 128
#define NEDGE 1600000
#define HID 512
#define OUTD 128
#define K1 (3*DD)   // 384 logical K (news 0..127, ent 128..255, top 256..383)
#define KX 256      // stored X (ent_agg, top_agg only)
#define NBKT 391    // ceil(100000/256) buckets of 256 nodes

typedef __bf16 bf16x8 __attribute__((ext_vector_type(8)));
typedef __bf16 bf16x4 __attribute__((ext_vector_type(4)));
typedef float  f32x4  __attribute__((ext_vector_type(4)));

__device__ __forceinline__ __bf16 f2b(float f) {
    __hip_bfloat16 h = __float2bfloat16(f);
    union { __hip_bfloat16 h; __bf16 b; } u; u.h = h; return u.b;
}

__device__ __forceinline__ void gll16(const void* g, void* l) {
    __builtin_amdgcn_global_load_lds((const __attribute__((address_space(1))) void*)g,
                                     (__attribute__((address_space(3))) void*)l, 16, 0, 0);
}

__device__ __forceinline__ float ftanh(float x) {
    x = fminf(fmaxf(x, -15.f), 15.f);
    float t = __expf(2.f * x);
    return (t - 1.f) / (t + 1.f);
}

// ---- convert feature tables to bf16 ----
__global__ void conv_feats(const float* __restrict__ entf, const float* __restrict__ topf,
                           __bf16* __restrict__ entb, __bf16* __restrict__ topb) {
    long i = ((long)blockIdx.x * 256 + threadIdx.x) * 4;
    const long NEL = (long)NE * DD;   // 6.4M
    if (i < NEL) {
        float4 v = *(const float4*)(entf + i);
        *(bf16x4*)(entb + i) = bf16x4{f2b(v.x), f2b(v.y), f2b(v.z), f2b(v.w)};
    } else {
        long j = i - NEL;
        float4 v = *(const float4*)(topf + j);
        *(bf16x4*)(topb + j) = bf16x4{f2b(v.x), f2b(v.y), f2b(v.z), f2b(v.w)};
    }
}

// ---- bucket histogram: LDS-local then one global atomic per (block,bucket) ----
__global__ __launch_bounds__(256) void hist_buckets(const int* __restrict__ er,
                                                    const int* __restrict__ tr,
                                                    int* __restrict__ bc_e,
                                                    int* __restrict__ bc_t) {
    __shared__ int lhe[NBKT], lht[NBKT];
    const int tid = threadIdx.x;
    for (int i = tid; i < NBKT; i += 256) { lhe[i] = 0; lht[i] = 0; }
    __syncthreads();
    const int base = blockIdx.x * 8192;
    #pragma unroll 4
    for (int k = 0; k < 32; k++) {
        int e = base + k * 256 + tid;
        if (e < NEDGE) {
            atomicAdd(&lhe[er[e] >> 8], 1);
            atomicAdd(&lht[tr[e] >> 8], 1);
        }
    }
    __syncthreads();
    for (int i = tid; i < NBKT; i += 256) {
        if (lhe[i]) atomicAdd(&bc_e[i], lhe[i]);
        if (lht[i]) atomicAdd(&bc_t[i], lht[i]);
    }
}

// ---- scan 391 bucket counts -> inclusive bc, exclusive cursors; offs[0]=0 ----
__global__ void scan_buckets(int* __restrict__ bc_e, int* __restrict__ bc_t,
                             int* __restrict__ cur_e, int* __restrict__ cur_t,
                             int* __restrict__ offs_e, int* __restrict__ offs_t) {
    int* bc  = blockIdx.y ? bc_t : bc_e;
    int* cur = blockIdx.y ? cur_t : cur_e;
    int* offs = blockIdx.y ? offs_t : offs_e;
    __shared__ int s[512];
    int i = threadIdx.x;
    s[i] = (i < NBKT) ? bc[i] : 0;
    __syncthreads();
    #pragma unroll
    for (int off = 1; off < 512; off <<= 1) {
        int v = (i >= off) ? s[i - off] : 0;
        __syncthreads();
        s[i] += v;
        __syncthreads();
    }
    if (i < NBKT) {
        bc[i] = s[i];
        cur[i] = i ? s[i - 1] : 0;
    }
    if (i == 0) offs[0] = 0;
}

// ---- partition edges into buckets ----
__global__ __launch_bounds__(256) void scatter_bucket(const int* __restrict__ er,
                                                      const int* __restrict__ ec,
                                                      const int* __restrict__ tr,
                                                      const int* __restrict__ tc,
                                                      int* __restrict__ cur_e,
                                                      int* __restrict__ cur_t,
                                                      int* __restrict__ be,
                                                      int* __restrict__ bt) {
    __shared__ int lhe[NBKT], lht[NBKT];   // counts, then local cursors
    __shared__ int lbe[NBKT], lbt[NBKT];   // reserved global bases
    const int tid = threadIdx.x;
    for (int i = tid; i < NBKT; i += 256) { lhe[i] = 0; lht[i] = 0; }
    __syncthreads();
    const int base = blockIdx.x * 4096;
    #pragma unroll 4
    for (int k = 0; k < 16; k++) {
        int e = base + k * 256 + tid;
        if (e < NEDGE) {
            atomicAdd(&lhe[er[e] >> 8], 1);
            atomicAdd(&lht[tr[e] >> 8], 1);
        }
    }
    __syncthreads();
    for (int i = tid; i < NBKT; i += 256) {
        int c = lhe[i];
        lbe[i] = c ? atomicAdd(&cur_e[i], c) : 0;
        lhe[i] = 0;
        c = lht[i];
        lbt[i] = c ? atomicAdd(&cur_t[i], c) : 0;
        lht[i] = 0;
    }
    __syncthreads();
    #pragma unroll 4
    for (int k = 0; k < 16; k++) {
        int e = base + k * 256 + tid;
        if (e < NEDGE) {
            int r = er[e];
            int b = r >> 8;
            int p = lbe[b] + atomicAdd(&lhe[b], 1);
            be[p] = ((r & 255) << 16) | ec[e];
            r = tr[e];
            b = r >> 8;
            p = lbt[b] + atomicAdd(&lht[b], 1);
            bt[p] = ((r & 255) << 16) | tc[e];
        }
    }
}

// ---- per-bucket exact CSR: local hist + scan -> offs + reorder cols ----
__global__ __launch_bounds__(256) void bucket_csr(const int* __restrict__ be,
                                                  const int* __restrict__ bt,
                                                  const int* __restrict__ bc_e,
                                                  const int* __restrict__ bc_t,
                                                  int* __restrict__ offs_e,
                                                  int* __restrict__ offs_t,
                                                  int* __restrict__ se,
                                                  int* __restrict__ st) {
    const int* buf = blockIdx.y ? bt : be;
    const int* bc  = blockIdx.y ? bc_t : bc_e;
    int* offs      = blockIdx.y ? offs_t : offs_e;
    int* sout      = blockIdx.y ? st : se;
    const int b = blockIdx.x;
    const int tid = threadIdx.x;
    const int start = b ? bc[b - 1] : 0;
    const int cnt = bc[b] - start;

    __shared__ int scn[256];
    __shared__ int lcur[256];
    scn[tid] = 0;
    __syncthreads();
    for (int i = tid; i < cnt; i += 256)
        atomicAdd(&scn[buf[start + i] >> 16], 1);
    __syncthreads();
    #pragma unroll
    for (int off = 1; off < 256; off <<= 1) {
        int v = (tid >= off) ? scn[tid - off] : 0;
        __syncthreads();
        scn[tid] += v;
        __syncthreads();
    }
    const int node = b * 256 + tid;
    if (node < NN) offs[node + 1] = start + scn[tid];
    lcur[tid] = start + (tid ? scn[tid - 1] : 0);
    __syncthreads();
    for (int i = tid; i < cnt; i += 256) {
        int v = buf[start + i];
        int p = atomicAdd(&lcur[v >> 16], 1);
        sout[p] = v & 0xFFFF;
    }
}

// ---- gather-aggregate (bf16 tables); X stores only [ent_agg | top_agg] ----
__global__ __launch_bounds__(256) void aggregate2(const __bf16* __restrict__ entb,
                                                  const __bf16* __restrict__ topb,
                                                  const int* __restrict__ offs_e,
                                                  const int* __restrict__ offs_t,
                                                  const int* __restrict__ se,
                                                  const int* __restrict__ st,
                                                  __bf16* __restrict__ X) {
    const int wave = threadIdx.x >> 6, lane = threadIdx.x & 63;
    const int node = blockIdx.x * 4 + wave;
    if (node >= NN) return;
    const int h = lane >> 4;        // 0..3: edge phase
    const int d = (lane & 15) * 8;  // dim group of 8

    float ea[8] = {0,0,0,0,0,0,0,0};
    float pa[8] = {0,0,0,0,0,0,0,0};

    const int s0 = offs_e[node], s1 = offs_e[node + 1];
    int i = s0 + h;
    for (; i + 12 < s1; i += 16) {
        int c0 = se[i], c1 = se[i + 4], c2 = se[i + 8], c3 = se[i + 12];
        bf16x8 v0 = *(const bf16x8*)(entb + (long)c0 * DD + d);
        bf16x8 v1 = *(const bf16x8*)(entb + (long)c1 * DD + d);
        bf16x8 v2 = *(const bf16x8*)(entb + (long)c2 * DD + d);
        bf16x8 v3 = *(const bf16x8*)(entb + (long)c3 * DD + d);
        #pragma unroll
        for (int j = 0; j < 8; j++)
            ea[j] += ((float)v0[j] + (float)v1[j]) + ((float)v2[j] + (float)v3[j]);
    }
    for (; i < s1; i += 4) {
        bf16x8 v = *(const bf16x8*)(entb + (long)se[i] * DD + d);
        #pragma unroll
        for (int j = 0; j < 8; j++) ea[j] += (float)v[j];
    }

    const int t0 = offs_t[node], t1 = offs_t[node + 1];
    i = t0 + h;
    for (; i + 12 < t1; i += 16) {
        int c0 = st[i], c1 = st[i + 4], c2 = st[i + 8], c3 = st[i + 12];
        bf16x8 v0 = *(const bf16x8*)(topb + (long)c0 * DD + d);
        bf16x8 v1 = *(const bf16x8*)(topb + (long)c1 * DD + d);
        bf16x8 v2 = *(const bf16x8*)(topb + (long)c2 * DD + d);
        bf16x8 v3 = *(const bf16x8*)(topb + (long)c3 * DD + d);
        #pragma unroll
        for (int j = 0; j < 8; j++)
            pa[j] += ((float)v0[j] + (float)v1[j]) + ((float)v2[j] + (float)v3[j]);
    }
    for (; i < t1; i += 4) {
        bf16x8 v = *(const bf16x8*)(topb + (long)st[i] * DD + d);
        #pragma unroll
        for (int j = 0; j < 8; j++) pa[j] += (float)v[j];
    }

    #pragma unroll
    for (int j = 0; j < 8; j++) {
        ea[j] += __shfl_xor(ea[j], 16, 64);
        ea[j] += __shfl_xor(ea[j], 32, 64);
        pa[j] += __shfl_xor(pa[j], 16, 64);
        pa[j] += __shfl_xor(pa[j], 32, 64);
    }

    const float ie = 1.0f / ((float)(s1 - s0) + 1e-8f);
    const float it = 1.0f / ((float)(t1 - t0) + 1e-8f);
    __bf16* xr = X + (long)node * KX;
    if (h == 1) {
        *(bf16x8*)(xr + d) = bf16x8{f2b(ea[0]*ie), f2b(ea[1]*ie), f2b(ea[2]*ie), f2b(ea[3]*ie),
                                    f2b(ea[4]*ie), f2b(ea[5]*ie), f2b(ea[6]*ie), f2b(ea[7]*ie)};
    } else if (h == 2) {
        *(bf16x8*)(xr + DD + d) = bf16x8{f2b(pa[0]*it), f2b(pa[1]*it), f2b(pa[2]*it), f2b(pa[3]*it),
                                         f2b(pa[4]*it), f2b(pa[5]*it), f2b(pa[6]*it), f2b(pa[7]*it)};
    }
}

// ---- W1 [384,512] -> W1T bf16 [512,384]; W2 [512,128] -> W2T bf16 [128,512] ----
__global__ void conv_w(const float* __restrict__ W1, const float* __restrict__ W2,
                       __bf16* __restrict__ W1T, __bf16* __restrict__ W2T) {
    int i = blockIdx.x * 256 + threadIdx.x;
    if (i < K1 * HID) {
        int k = i / HID, n = i % HID;
        W1T[n * K1 + k] = f2b(W1[i]);
    } else {
        int j = i - K1 * HID;
        if (j < HID * OUTD) {
            int k = j / OUTD, n = j % OUTD;
            W2T[n * HID + k] = f2b(W2[j]);
        }
    }
}

// ======== fused MLP: out = (tanh([news|X]@W1T^T + b1)) @ W2T^T + b2 ========
// 128-row tile per block; loop over 4 HID-chunks. XOR swizzle keeps
// global_load_lds coalesced AND fragment ds_read_b128 at 2-way aliasing (free).

// stage a [128 x 32] bf16 tile (swizzled) from row-major bf16 src via global_load_lds
__device__ __forceinline__ void stage_tile(const __bf16* __restrict__ src, int ldK,
                                           int k0, int row0, int rowmax,
                                           __bf16* lds, int w, int lane) {
    #pragma unroll
    for (int half = 0; half < 2; half++) {
        int ss = w * 64 + half * 256 + lane;
        int r = ss >> 2;
        int sw = (r & 3) ^ ((r >> 2) & 3);
        int c = (ss & 3) ^ sw;
        int gr = row0 + r; if (gr >= rowmax) gr = rowmax - 1;
        gll16(src + (long)gr * ldK + k0 + c * 8,
              lds + (w * 64 + half * 256) * 8);
    }
}

// stage a [128 x 32] tile (same swizzled layout) from row-major f32 src (reg-staged)
__device__ __forceinline__ void stage_tile_f32(const float* __restrict__ src, int ldK,
                                               int k0, int row0, int rowmax,
                                               __bf16* lds, int w, int lane) {
    #pragma unroll
    for (int half = 0; half < 2; half++) {
        int ss = w * 64 + half * 256 + lane;
        int r = ss >> 2;
        int sw = (r & 3) ^ ((r >> 2) & 3);
        int c = (ss & 3) ^ sw;
        int gr = row0 + r; if (gr >= rowmax) gr = rowmax - 1;
        const float* p = src + (long)gr * ldK + k0 + c * 8;
        float4 a = *(const float4*)p;
        float4 b = *(const float4*)(p + 4);
        *(bf16x8*)(lds + (long)ss * 8) = bf16x8{f2b(a.x), f2b(a.y), f2b(a.z), f2b(a.w),
                                                f2b(b.x), f2b(b.y), f2b(b.z), f2b(b.w)};
    }
}

// read fragment (logical row r, k-chunk q) from swizzled [128 x 32] tile
__device__ __forceinline__ bf16x8 frag(const __bf16* lds, int r, int q) {
    int sw = (r & 3) ^ ((r >> 2) & 3);
    return *(const bf16x8*)(lds + (r * 4 + (q ^ sw)) * 8);
}

// Hs [128 rows x 128 k] swizzled: chunk16 = kk*4+quad
__device__ __forceinline__ void hs_write(__bf16* Hs, int r, int c, __bf16 v) {
    int ch = c >> 3;
    int pch = ((((ch >> 2) ^ ((r >> 2) & 3)) << 2) | ((ch & 3) ^ (r & 3)));
    Hs[(r * 16 + pch) * 8 + (c & 7)] = v;
}
__device__ __forceinline__ bf16x8 hs_frag(const __bf16* Hs, int r, int kk, int q) {
    int pch = (((kk ^ ((r >> 2) & 3)) << 2) | (q ^ (r & 3)));
    return *(const bf16x8*)(Hs + (r * 16 + pch) * 8);
}

__global__ __launch_bounds__(256, 2) void mlp_fused(const float* __restrict__ news,
                                                    const __bf16* __restrict__ X,
                                                    const __bf16* __restrict__ W1T,
                                                    const float* __restrict__ b1,
                                                    const __bf16* __restrict__ W2T,
                                                    const float* __restrict__ b2,
                                                    float* __restrict__ out) {
    __shared__ __bf16 Xs[128 * 32];    // 8 KB
    __shared__ __bf16 Ws[128 * 32];    // 8 KB (W1 rows, then W2 rows)
    __shared__ __bf16 Hs[128 * 128];   // 32 KB
    const int bm = blockIdx.x * 128;
    const int t = threadIdx.x;
    const int lane = t & 63;
    const int w = t >> 6;
    const int quad = lane >> 4;
    const int l16 = lane & 15;
    const int wm = w >> 1, wn = w & 1;

    f32x4 oacc[4][4];
    #pragma unroll
    for (int i = 0; i < 4; i++)
        #pragma unroll
        for (int j = 0; j < 4; j++)
            #pragma unroll
            for (int r = 0; r < 4; r++) oacc[i][j][r] = 0.0f;

    for (int nc = 0; nc < 4; nc++) {
        // ---- H-chunk: H[128 x 128] = Xrow_tile @ W1T[nc*128..+128]^T ----
        f32x4 hacc[4][4];
        #pragma unroll
        for (int i = 0; i < 4; i++)
            #pragma unroll
            for (int j = 0; j < 4; j++)
                #pragma unroll
                for (int r = 0; r < 4; r++) hacc[i][j][r] = 0.0f;

        for (int kt = 0; kt < K1 / 32; kt++) {
            __syncthreads();
            if (kt < 4) stage_tile_f32(news, DD, kt * 32, bm, NN, Xs, w, lane);
            else        stage_tile(X, KX, (kt - 4) * 32, bm, NN, Xs, w, lane);
            stage_tile(W1T, K1, kt * 32, nc * 128, HID, Ws, w, lane);
            __syncthreads();
            bf16x8 af[4], bfr[4];
            #pragma unroll
            for (int i = 0; i < 4; i++) {
                af[i]  = frag(Xs, wm * 64 + i * 16 + l16, quad);
                bfr[i] = frag(Ws, wn * 64 + i * 16 + l16, quad);
            }
            #pragma unroll
            for (int i = 0; i < 4; i++)
                #pragma unroll
                for (int j = 0; j < 4; j++)
                    hacc[i][j] = __builtin_amdgcn_mfma_f32_16x16x32_bf16(af[i], bfr[j], hacc[i][j], 0, 0, 0);
        }

        // bias + tanh -> Hs (C/D layout: row=quad*4+reg, col=l16)
        #pragma unroll
        for (int j = 0; j < 4; j++) {
            const int col = wn * 64 + j * 16 + l16;
            const float bb = b1[nc * 128 + col];
            #pragma unroll
            for (int i = 0; i < 4; i++) {
                const int rbase = wm * 64 + i * 16 + quad * 4;
                #pragma unroll
                for (int r = 0; r < 4; r++)
                    hs_write(Hs, rbase + r, col, f2b(ftanh(hacc[i][j][r] + bb)));
            }
        }

        // ---- O += H_chunk @ W2T[:, nc*128..+128]^T ----
        for (int kk = 0; kk < 4; kk++) {
            __syncthreads();
            stage_tile(W2T, HID, nc * 128 + kk * 32, 0, OUTD, Ws, w, lane);
            __syncthreads();
            bf16x8 af[4], bfr[4];
            #pragma unroll
            for (int i = 0; i < 4; i++) {
                af[i]  = hs_frag(Hs, wm * 64 + i * 16 + l16, kk, quad);
                bfr[i] = frag(Ws, wn * 64 + i * 16 + l16, quad);
            }
            #pragma unroll
            for (int i = 0; i < 4; i++)
                #pragma unroll
                for (int j = 0; j < 4; j++)
                    oacc[i][j] = __builtin_amdgcn_mfma_f32_16x16x32_bf16(af[i], bfr[j], oacc[i][j], 0, 0, 0);
        }
    }

    // epilogue: out f32 [NN x 128]
    #pragma unroll
    for (int j = 0; j < 4; j++) {
        const int gc = wn * 64 + j * 16 + l16;
        const float bb = b2[gc];
        #pragma unroll
        for (int i = 0; i < 4; i++) {
            const int rbase = bm + wm * 64 + i * 16 + quad * 4;
            #pragma unroll
            for (int r = 0; r < 4; r++) {
                const int gr = rbase + r;
                if (gr < NN) out[(long)gr * OUTD + gc] = oacc[i][j][r] + bb;
            }
        }
    }
}

extern "C" void kernel_launch(void* const* d_in, const int* in_sizes, int n_in,
                              void* d_out, int out_size, void* d_ws, size_t ws_size,
                              hipStream_t stream) {
    const float* news  = (const float*)d_in[0];
    const float* ent_f = (const float*)d_in[1];
    const float* top_f = (const float*)d_in[2];
    const int* ent_row = (const int*)d_in[3];
    const int* ent_col = (const int*)d_in[4];
    const int* top_row = (const int*)d_in[5];
    const int* top_col = (const int*)d_in[6];
    const float* W1 = (const float*)d_in[7];
    const float* b1 = (const float*)d_in[8];
    const float* W2 = (const float*)d_in[9];
    const float* b2 = (const float*)d_in[10];

    char* ws = (char*)d_ws;
    //   [0,       400016)    offs_e int[100001]
    //   [400016,  800032)    offs_t int[100001]
    //   [800032,  801596)    bc_e   int[391]
    //   [801596,  803160)    bc_t   int[391]
    //   [803160,  804724)    cur_e  int[391]
    //   [804724,  806288)    cur_t  int[391]
    //   [806320,  7206320)   be packed int[1.6M]
    //   [7206320, 13606320)  bt packed int[1.6M]
    //   [13606320,20006320)  se int[1.6M]
    //   [20006320,26406320)  st int[1.6M]
    //   [26406336,39206336)  entb bf16 [50000*128]
    //   [39206336,39718336)  topb bf16 [2000*128]
    //   [102400000,153600000) X bf16 [100000*256]  (ent_agg | top_agg)
    //   [179200000,179593216) W1T bf16 [512*384]
    //   [179593216,179724288) W2T bf16 [128*512]
    int* offs_e = (int*)(ws + 0);
    int* offs_t = (int*)(ws + 400016);
    int* bc_e   = (int*)(ws + 800032);
    int* bc_t   = (int*)(ws + 801596);
    int* cur_e  = (int*)(ws + 803160);
    int* cur_t  = (int*)(ws + 804724);
    int* be     = (int*)(ws + 806320);
    int* bt     = (int*)(ws + 7206320);
    int* se     = (int*)(ws + 13606320);
    int* st     = (int*)(ws + 20006320);
    __bf16* entb = (__bf16*)(ws + 26406336);
    __bf16* topb = (__bf16*)(ws + 39206336);
    __bf16* X   = (__bf16*)(ws + 102400000);
    __bf16* W1T = (__bf16*)(ws + 179200000);
    __bf16* W2T = (__bf16*)(ws + 179593216);

    hipMemsetAsync(ws + 800032, 0, 6256, stream);   // zero bc/cur arrays
    conv_w<<<1024, 256, 0, stream>>>(W1, W2, W1T, W2T);
    conv_feats<<<6500, 256, 0, stream>>>(ent_f, top_f, entb, topb);
    hist_buckets<<<196, 256, 0, stream>>>(ent_row, top_row, bc_e, bc_t);
    scan_buckets<<<dim3(1, 2), 512, 0, stream>>>(bc_e, bc_t, cur_e, cur_t, offs_e, offs_t);
    scatter_bucket<<<392, 256, 0, stream>>>(ent_row, ent_col, top_row, top_col,
                                            cur_e, cur_t, be, bt);
    bucket_csr<<<dim3(NBKT, 2), 256, 0, stream>>>(be, bt, bc_e, bc_t,
                                                  offs_e, offs_t, se, st);
    aggregate2<<<NN / 4, 256, 0, stream>>>(entb, topb, offs_e, offs_t, se, st, X);
    mlp_fused<<<782, 256, 0, stream>>>(news, X, W1T, b1, W2T, b2, (float*)d_out);
}

// Round 2
// 540.356 us; speedup vs baseline: 1.0382x; 1.0382x over previous
//
#include <hip/hip_runtime.h>
#include <hip/hip_bf16.h>

#define NN 100000
#define NE 50000
#define NT 2000
#define DD 128
#define NEDGE 1600000
#define HID 512
#define OUTD 128
#define K1 (3*DD)   // 384: X layout [news | ent_agg | top_agg]
#define NBKT 391    // ceil(100000/256) buckets of 256 nodes

typedef __bf16 bf16x8 __attribute__((ext_vector_type(8)));
typedef __bf16 bf16x4 __attribute__((ext_vector_type(4)));
typedef float  f32x4  __attribute__((ext_vector_type(4)));

__device__ __forceinline__ __bf16 f2b(float f) {
    __hip_bfloat16 h = __float2bfloat16(f);
    union { __hip_bfloat16 h; __bf16 b; } u; u.h = h; return u.b;
}

__device__ __forceinline__ void gll16(const void* g, void* l) {
    __builtin_amdgcn_global_load_lds((const __attribute__((address_space(1))) void*)g,
                                     (__attribute__((address_space(3))) void*)l, 16, 0, 0);
}

__device__ __forceinline__ float ftanh(float x) {
    x = fminf(fmaxf(x, -15.f), 15.f);
    float t = __expf(2.f * x);
    return (t - 1.f) / (t + 1.f);
}

// ---- convert: ent/top tables -> bf16 tables; news -> bf16 into X cols 0..127 ----
__global__ void conv_feats(const float* __restrict__ entf, const float* __restrict__ topf,
                           const float* __restrict__ news,
                           __bf16* __restrict__ entb, __bf16* __restrict__ topb,
                           __bf16* __restrict__ X) {
    long i = ((long)blockIdx.x * 256 + threadIdx.x) * 4;
    const long NEL = (long)NE * DD;            // 6.4M
    const long NTL = (long)NT * DD;            // 0.256M
    if (i < NEL) {
        float4 v = *(const float4*)(entf + i);
        *(bf16x4*)(entb + i) = bf16x4{f2b(v.x), f2b(v.y), f2b(v.z), f2b(v.w)};
    } else if (i < NEL + NTL) {
        long j = i - NEL;
        float4 v = *(const float4*)(topf + j);
        *(bf16x4*)(topb + j) = bf16x4{f2b(v.x), f2b(v.y), f2b(v.z), f2b(v.w)};
    } else {
        long j = i - NEL - NTL;                // 0 .. 12.8M
        long row = j >> 7, col = j & 127;      // news [NN x 128], 4-aligned col
        float4 v = *(const float4*)(news + j);
        *(bf16x4*)(X + row * K1 + col) = bf16x4{f2b(v.x), f2b(v.y), f2b(v.z), f2b(v.w)};
    }
}

// ---- bucket histogram: LDS-local then one global atomic per (block,bucket) ----
__global__ __launch_bounds__(256) void hist_buckets(const int* __restrict__ er,
                                                    const int* __restrict__ tr,
                                                    int* __restrict__ bc_e,
                                                    int* __restrict__ bc_t) {
    __shared__ int lhe[NBKT], lht[NBKT];
    const int tid = threadIdx.x;
    for (int i = tid; i < NBKT; i += 256) { lhe[i] = 0; lht[i] = 0; }
    __syncthreads();
    const int base = blockIdx.x * 8192;
    #pragma unroll 4
    for (int k = 0; k < 32; k++) {
        int e = base + k * 256 + tid;
        if (e < NEDGE) {
            atomicAdd(&lhe[er[e] >> 8], 1);
            atomicAdd(&lht[tr[e] >> 8], 1);
        }
    }
    __syncthreads();
    for (int i = tid; i < NBKT; i += 256) {
        if (lhe[i]) atomicAdd(&bc_e[i], lhe[i]);
        if (lht[i]) atomicAdd(&bc_t[i], lht[i]);
    }
}

// ---- scan 391 bucket counts -> inclusive bc, exclusive cursors; offs[0]=0 ----
__global__ void scan_buckets(int* __restrict__ bc_e, int* __restrict__ bc_t,
                             int* __restrict__ cur_e, int* __restrict__ cur_t,
                             int* __restrict__ offs_e, int* __restrict__ offs_t) {
    int* bc  = blockIdx.y ? bc_t : bc_e;
    int* cur = blockIdx.y ? cur_t : cur_e;
    int* offs = blockIdx.y ? offs_t : offs_e;
    __shared__ int s[512];
    int i = threadIdx.x;
    s[i] = (i < NBKT) ? bc[i] : 0;
    __syncthreads();
    #pragma unroll
    for (int off = 1; off < 512; off <<= 1) {
        int v = (i >= off) ? s[i - off] : 0;
        __syncthreads();
        s[i] += v;
        __syncthreads();
    }
    if (i < NBKT) {
        bc[i] = s[i];
        cur[i] = i ? s[i - 1] : 0;
    }
    if (i == 0) offs[0] = 0;
}

// ---- partition edges into buckets ----
__global__ __launch_bounds__(256) void scatter_bucket(const int* __restrict__ er,
                                                      const int* __restrict__ ec,
                                                      const int* __restrict__ tr,
                                                      const int* __restrict__ tc,
                                                      int* __restrict__ cur_e,
                                                      int* __restrict__ cur_t,
                                                      int* __restrict__ be,
                                                      int* __restrict__ bt) {
    __shared__ int lhe[NBKT], lht[NBKT];   // counts, then local cursors
    __shared__ int lbe[NBKT], lbt[NBKT];   // reserved global bases
    const int tid = threadIdx.x;
    for (int i = tid; i < NBKT; i += 256) { lhe[i] = 0; lht[i] = 0; }
    __syncthreads();
    const int base = blockIdx.x * 4096;
    #pragma unroll 4
    for (int k = 0; k < 16; k++) {
        int e = base + k * 256 + tid;
        if (e < NEDGE) {
            atomicAdd(&lhe[er[e] >> 8], 1);
            atomicAdd(&lht[tr[e] >> 8], 1);
        }
    }
    __syncthreads();
    for (int i = tid; i < NBKT; i += 256) {
        int c = lhe[i];
        lbe[i] = c ? atomicAdd(&cur_e[i], c) : 0;
        lhe[i] = 0;
        c = lht[i];
        lbt[i] = c ? atomicAdd(&cur_t[i], c) : 0;
        lht[i] = 0;
    }
    __syncthreads();
    #pragma unroll 4
    for (int k = 0; k < 16; k++) {
        int e = base + k * 256 + tid;
        if (e < NEDGE) {
            int r = er[e];
            int b = r >> 8;
            int p = lbe[b] + atomicAdd(&lhe[b], 1);
            be[p] = ((r & 255) << 16) | ec[e];
            r = tr[e];
            b = r >> 8;
            p = lbt[b] + atomicAdd(&lht[b], 1);
            bt[p] = ((r & 255) << 16) | tc[e];
        }
    }
}

// ---- per-bucket exact CSR: local hist + scan -> offs + reorder cols ----
__global__ __launch_bounds__(256) void bucket_csr(const int* __restrict__ be,
                                                  const int* __restrict__ bt,
                                                  const int* __restrict__ bc_e,
                                                  const int* __restrict__ bc_t,
                                                  int* __restrict__ offs_e,
                                                  int* __restrict__ offs_t,
                                                  int* __restrict__ se,
                                                  int* __restrict__ st) {
    const int* buf = blockIdx.y ? bt : be;
    const int* bc  = blockIdx.y ? bc_t : bc_e;
    int* offs      = blockIdx.y ? offs_t : offs_e;
    int* sout      = blockIdx.y ? st : se;
    const int b = blockIdx.x;
    const int tid = threadIdx.x;
    const int start = b ? bc[b - 1] : 0;
    const int cnt = bc[b] - start;

    __shared__ int scn[256];
    __shared__ int lcur[256];
    scn[tid] = 0;
    __syncthreads();
    for (int i = tid; i < cnt; i += 256)
        atomicAdd(&scn[buf[start + i] >> 16], 1);
    __syncthreads();
    #pragma unroll
    for (int off = 1; off < 256; off <<= 1) {
        int v = (tid >= off) ? scn[tid - off] : 0;
        __syncthreads();
        scn[tid] += v;
        __syncthreads();
    }
    const int node = b * 256 + tid;
    if (node < NN) offs[node + 1] = start + scn[tid];
    lcur[tid] = start + (tid ? scn[tid - 1] : 0);
    __syncthreads();
    for (int i = tid; i < cnt; i += 256) {
        int v = buf[start + i];
        int p = atomicAdd(&lcur[v >> 16], 1);
        sout[p] = v & 0xFFFF;
    }
}

// ---- gather-aggregate (bf16 tables) -> X cols 128..383 ----
__global__ __launch_bounds__(256) void aggregate2(const __bf16* __restrict__ entb,
                                                  const __bf16* __restrict__ topb,
                                                  const int* __restrict__ offs_e,
                                                  const int* __restrict__ offs_t,
                                                  const int* __restrict__ se,
                                                  const int* __restrict__ st,
                                                  __bf16* __restrict__ X) {
    const int wave = threadIdx.x >> 6, lane = threadIdx.x & 63;
    const int node = blockIdx.x * 4 + wave;
    if (node >= NN) return;
    const int h = lane >> 4;        // 0..3: edge phase
    const int d = (lane & 15) * 8;  // dim group of 8

    float ea[8] = {0,0,0,0,0,0,0,0};
    float pa[8] = {0,0,0,0,0,0,0,0};

    const int s0 = offs_e[node], s1 = offs_e[node + 1];
    int i = s0 + h;
    for (; i + 12 < s1; i += 16) {
        int c0 = se[i], c1 = se[i + 4], c2 = se[i + 8], c3 = se[i + 12];
        bf16x8 v0 = *(const bf16x8*)(entb + (long)c0 * DD + d);
        bf16x8 v1 = *(const bf16x8*)(entb + (long)c1 * DD + d);
        bf16x8 v2 = *(const bf16x8*)(entb + (long)c2 * DD + d);
        bf16x8 v3 = *(const bf16x8*)(entb + (long)c3 * DD + d);
        #pragma unroll
        for (int j = 0; j < 8; j++)
            ea[j] += ((float)v0[j] + (float)v1[j]) + ((float)v2[j] + (float)v3[j]);
    }
    for (; i < s1; i += 4) {
        bf16x8 v = *(const bf16x8*)(entb + (long)se[i] * DD + d);
        #pragma unroll
        for (int j = 0; j < 8; j++) ea[j] += (float)v[j];
    }

    const int t0 = offs_t[node], t1 = offs_t[node + 1];
    i = t0 + h;
    for (; i + 12 < t1; i += 16) {
        int c0 = st[i], c1 = st[i + 4], c2 = st[i + 8], c3 = st[i + 12];
        bf16x8 v0 = *(const bf16x8*)(topb + (long)c0 * DD + d);
        bf16x8 v1 = *(const bf16x8*)(topb + (long)c1 * DD + d);
        bf16x8 v2 = *(const bf16x8*)(topb + (long)c2 * DD + d);
        bf16x8 v3 = *(const bf16x8*)(topb + (long)c3 * DD + d);
        #pragma unroll
        for (int j = 0; j < 8; j++)
            pa[j] += ((float)v0[j] + (float)v1[j]) + ((float)v2[j] + (float)v3[j]);
    }
    for (; i < t1; i += 4) {
        bf16x8 v = *(const bf16x8*)(topb + (long)st[i] * DD + d);
        #pragma unroll
        for (int j = 0; j < 8; j++) pa[j] += (float)v[j];
    }

    #pragma unroll
    for (int j = 0; j < 8; j++) {
        ea[j] += __shfl_xor(ea[j], 16, 64);
        ea[j] += __shfl_xor(ea[j], 32, 64);
        pa[j] += __shfl_xor(pa[j], 16, 64);
        pa[j] += __shfl_xor(pa[j], 32, 64);
    }

    const float ie = 1.0f / ((float)(s1 - s0) + 1e-8f);
    const float it = 1.0f / ((float)(t1 - t0) + 1e-8f);
    __bf16* xr = X + (long)node * K1;
    if (h == 1) {
        *(bf16x8*)(xr + DD + d) = bf16x8{f2b(ea[0]*ie), f2b(ea[1]*ie), f2b(ea[2]*ie), f2b(ea[3]*ie),
                                         f2b(ea[4]*ie), f2b(ea[5]*ie), f2b(ea[6]*ie), f2b(ea[7]*ie)};
    } else if (h == 2) {
        *(bf16x8*)(xr + 2*DD + d) = bf16x8{f2b(pa[0]*it), f2b(pa[1]*it), f2b(pa[2]*it), f2b(pa[3]*it),
                                           f2b(pa[4]*it), f2b(pa[5]*it), f2b(pa[6]*it), f2b(pa[7]*it)};
    }
}

// ---- W1 [384,512] -> W1T bf16 [512,384]; W2 [512,128] -> W2T bf16 [128,512] ----
__global__ void conv_w(const float* __restrict__ W1, const float* __restrict__ W2,
                       __bf16* __restrict__ W1T, __bf16* __restrict__ W2T) {
    int i = blockIdx.x * 256 + threadIdx.x;
    if (i < K1 * HID) {
        int k = i / HID, n = i % HID;
        W1T[n * K1 + k] = f2b(W1[i]);
    } else {
        int j = i - K1 * HID;
        if (j < HID * OUTD) {
            int k = j / OUTD, n = j % OUTD;
            W2T[n * HID + k] = f2b(W2[j]);
        }
    }
}

// ======== fused MLP: out = (tanh(X@W1T^T + b1)) @ W2T^T + b2 ========
// 2-phase double-buffered pipeline: prefetch tile t+1 (global_load_lds) BEFORE
// computing tile t; the end-of-phase __syncthreads drains a load that had a
// whole MFMA phase in flight. Prefetch chain crosses kt->kk->next-nc bounds.

// stage a [128 x 32] bf16 tile (swizzled) from row-major bf16 src via global_load_lds
__device__ __forceinline__ void stage_tile(const __bf16* __restrict__ src, int ldK,
                                           int k0, int row0, int rowmax,
                                           __bf16* lds, int w, int lane) {
    #pragma unroll
    for (int half = 0; half < 2; half++) {
        int ss = w * 64 + half * 256 + lane;
        int r = ss >> 2;
        int sw = (r & 3) ^ ((r >> 2) & 3);
        int c = (ss & 3) ^ sw;
        int gr = row0 + r; if (gr >= rowmax) gr = rowmax - 1;
        gll16(src + (long)gr * ldK + k0 + c * 8,
              lds + (w * 64 + half * 256) * 8);
    }
}

// read fragment (logical row r, k-chunk q) from swizzled [128 x 32] tile
__device__ __forceinline__ bf16x8 frag(const __bf16* lds, int r, int q) {
    int sw = (r & 3) ^ ((r >> 2) & 3);
    return *(const bf16x8*)(lds + (r * 4 + (q ^ sw)) * 8);
}

// Hs [128 rows x 128 k] swizzled: chunk16 = kk*4+quad
__device__ __forceinline__ void hs_write(__bf16* Hs, int r, int c, __bf16 v) {
    int ch = c >> 3;
    int pch = ((((ch >> 2) ^ ((r >> 2) & 3)) << 2) | ((ch & 3) ^ (r & 3)));
    Hs[(r * 16 + pch) * 8 + (c & 7)] = v;
}
__device__ __forceinline__ bf16x8 hs_frag(const __bf16* Hs, int r, int kk, int q) {
    int pch = (((kk ^ ((r >> 2) & 3)) << 2) | (q ^ (r & 3)));
    return *(const bf16x8*)(Hs + (r * 16 + pch) * 8);
}

__global__ __launch_bounds__(256, 2) void mlp_fused(const __bf16* __restrict__ X,
                                                    const __bf16* __restrict__ W1T,
                                                    const float* __restrict__ b1,
                                                    const __bf16* __restrict__ W2T,
                                                    const float* __restrict__ b2,
                                                    float* __restrict__ out) {
    __shared__ __bf16 Xs[2][128 * 32];  // 2 x 8 KB
    __shared__ __bf16 Ws[2][128 * 32];  // 2 x 8 KB
    __shared__ __bf16 Hs[128 * 128];    // 32 KB
    const int bm = blockIdx.x * 128;
    const int t = threadIdx.x;
    const int lane = t & 63;
    const int w = t >> 6;
    const int quad = lane >> 4;
    const int l16 = lane & 15;
    const int wm = w >> 1, wn = w & 1;

    f32x4 oacc[4][4];
    #pragma unroll
    for (int i = 0; i < 4; i++)
        #pragma unroll
        for (int j = 0; j < 4; j++)
            #pragma unroll
            for (int r = 0; r < 4; r++) oacc[i][j][r] = 0.0f;

    // prologue: stage kt=0 tiles (X, W1 chunk nc=0) into buffer 0
    stage_tile(X,   K1, 0, bm, NN,  Xs[0], w, lane);
    stage_tile(W1T, K1, 0, 0,  HID, Ws[0], w, lane);
    int cur = 0;
    __syncthreads();   // drains vmcnt(0) + barrier

    for (int nc = 0; nc < 4; nc++) {
        f32x4 hacc[4][4];
        #pragma unroll
        for (int i = 0; i < 4; i++)
            #pragma unroll
            for (int j = 0; j < 4; j++)
                #pragma unroll
                for (int r = 0; r < 4; r++) hacc[i][j][r] = 0.0f;

        for (int kt = 0; kt < 12; kt++) {
            const int nb = cur ^ 1;
            if (kt < 11) {
                // prefetch next K-step of this H-chunk
                stage_tile(X,   K1, (kt + 1) * 32, bm,       NN,  Xs[nb], w, lane);
                stage_tile(W1T, K1, (kt + 1) * 32, nc * 128, HID, Ws[nb], w, lane);
            } else {
                // prefetch first W2 tile; its latency hides under tanh pass
                stage_tile(W2T, HID, nc * 128, 0, OUTD, Ws[nb], w, lane);
            }
            bf16x8 af[4], bfr[4];
            #pragma unroll
            for (int i = 0; i < 4; i++) {
                af[i]  = frag(Xs[cur], wm * 64 + i * 16 + l16, quad);
                bfr[i] = frag(Ws[cur], wn * 64 + i * 16 + l16, quad);
            }
            __builtin_amdgcn_s_setprio(1);
            #pragma unroll
            for (int i = 0; i < 4; i++)
                #pragma unroll
                for (int j = 0; j < 4; j++)
                    hacc[i][j] = __builtin_amdgcn_mfma_f32_16x16x32_bf16(af[i], bfr[j], hacc[i][j], 0, 0, 0);
            __builtin_amdgcn_s_setprio(0);
            __syncthreads();
            cur = nb;
        }

        // bias + tanh -> Hs (C/D layout: row=quad*4+reg, col=l16)
        #pragma unroll
        for (int j = 0; j < 4; j++) {
            const int col = wn * 64 + j * 16 + l16;
            const float bb = b1[nc * 128 + col];
            #pragma unroll
            for (int i = 0; i < 4; i++) {
                const int rbase = wm * 64 + i * 16 + quad * 4;
                #pragma unroll
                for (int r = 0; r < 4; r++)
                    hs_write(Hs, rbase + r, col, f2b(ftanh(hacc[i][j][r] + bb)));
            }
        }
        __syncthreads();   // Hs visible to wn-partner waves; W2 kk=0 tile landed

        // ---- O += H_chunk @ W2T[:, nc*128..+128]^T ----
        for (int kk = 0; kk < 4; kk++) {
            const int nb = cur ^ 1;
            if (kk < 3) {
                stage_tile(W2T, HID, nc * 128 + (kk + 1) * 32, 0, OUTD, Ws[nb], w, lane);
            } else if (nc < 3) {
                // prefetch next nc's first K-step (X + W1)
                stage_tile(X,   K1, 0, bm,             NN,  Xs[nb], w, lane);
                stage_tile(W1T, K1, 0, (nc + 1) * 128, HID, Ws[nb], w, lane);
            }
            bf16x8 af[4], bfr[4];
            #pragma unroll
            for (int i = 0; i < 4; i++) {
                af[i]  = hs_frag(Hs, wm * 64 + i * 16 + l16, kk, quad);
                bfr[i] = frag(Ws[cur], wn * 64 + i * 16 + l16, quad);
            }
            __builtin_amdgcn_s_setprio(1);
            #pragma unroll
            for (int i = 0; i < 4; i++)
                #pragma unroll
                for (int j = 0; j < 4; j++)
                    oacc[i][j] = __builtin_amdgcn_mfma_f32_16x16x32_bf16(af[i], bfr[j], oacc[i][j], 0, 0, 0);
            __builtin_amdgcn_s_setprio(0);
            __syncthreads();
            cur = nb;
        }
    }

    // epilogue: out f32 [NN x 128]; j innermost -> full-line coverage fast
    float bb[4];
    #pragma unroll
    for (int j = 0; j < 4; j++) bb[j] = b2[wn * 64 + j * 16 + l16];
    #pragma unroll
    for (int i = 0; i < 4; i++) {
        #pragma unroll
        for (int r = 0; r < 4; r++) {
            const int gr = bm + wm * 64 + i * 16 + quad * 4 + r;
            if (gr < NN) {
                float* orow = out + (long)gr * OUTD + wn * 64 + l16;
                #pragma unroll
                for (int j = 0; j < 4; j++)
                    orow[j * 16] = oacc[i][j][r] + bb[j];
            }
        }
    }
}

extern "C" void kernel_launch(void* const* d_in, const int* in_sizes, int n_in,
                              void* d_out, int out_size, void* d_ws, size_t ws_size,
                              hipStream_t stream) {
    const float* news  = (const float*)d_in[0];
    const float* ent_f = (const float*)d_in[1];
    const float* top_f = (const float*)d_in[2];
    const int* ent_row = (const int*)d_in[3];
    const int* ent_col = (const int*)d_in[4];
    const int* top_row = (const int*)d_in[5];
    const int* top_col = (const int*)d_in[6];
    const float* W1 = (const float*)d_in[7];
    const float* b1 = (const float*)d_in[8];
    const float* W2 = (const float*)d_in[9];
    const float* b2 = (const float*)d_in[10];

    char* ws = (char*)d_ws;
    //   [0,       400016)    offs_e int[100001]
    //   [400016,  800032)    offs_t int[100001]
    //   [800032,  801596)    bc_e   int[391]
    //   [801596,  803160)    bc_t   int[391]
    //   [803160,  804724)    cur_e  int[391]
    //   [804724,  806288)    cur_t  int[391]
    //   [806320,  7206320)   be packed int[1.6M]
    //   [7206320, 13606320)  bt packed int[1.6M]
    //   [13606320,20006320)  se int[1.6M]
    //   [20006320,26406320)  st int[1.6M]
    //   [26406336,39206336)  entb bf16 [50000*128]
    //   [39206336,39718336)  topb bf16 [2000*128]
    //   [102400000,179200000) X bf16 [100000*384] = [news | ent_agg | top_agg]
    //   [179200000,179593216) W1T bf16 [512*384]
    //   [179593216,179724288) W2T bf16 [128*512]
    int* offs_e = (int*)(ws + 0);
    int* offs_t = (int*)(ws + 400016);
    int* bc_e   = (int*)(ws + 800032);
    int* bc_t   = (int*)(ws + 801596);
    int* cur_e  = (int*)(ws + 803160);
    int* cur_t  = (int*)(ws + 804724);
    int* be     = (int*)(ws + 806320);
    int* bt     = (int*)(ws + 7206320);
    int* se     = (int*)(ws + 13606320);
    int* st     = (int*)(ws + 20006320);
    __bf16* entb = (__bf16*)(ws + 26406336);
    __bf16* topb = (__bf16*)(ws + 39206336);
    __bf16* X   = (__bf16*)(ws + 102400000);
    __bf16* W1T = (__bf16*)(ws + 179200000);
    __bf16* W2T = (__bf16*)(ws + 179593216);

    hipMemsetAsync(ws + 800032, 0, 6256, stream);   // zero bc/cur arrays
    conv_w<<<1024, 256, 0, stream>>>(W1, W2, W1T, W2T);
    conv_feats<<<19000, 256, 0, stream>>>(ent_f, top_f, news, entb, topb, X);
    hist_buckets<<<196, 256, 0, stream>>>(ent_row, top_row, bc_e, bc_t);
    scan_buckets<<<dim3(1, 2), 512, 0, stream>>>(bc_e, bc_t, cur_e, cur_t, offs_e, offs_t);
    scatter_bucket<<<392, 256, 0, stream>>>(ent_row, ent_col, top_row, top_col,
                                            cur_e, cur_t, be, bt);
    bucket_csr<<<dim3(NBKT, 2), 256, 0, stream>>>(be, bt, bc_e, bc_t,
                                                  offs_e, offs_t, se, st);
    aggregate2<<<NN / 4, 256, 0, stream>>>(entb, topb, offs_e, offs_t, se, st, X);
    mlp_fused<<<782, 256, 0, stream>>>(X, W1T, b1, W2T, b2, (float*)d_out);
}

// Round 4
// 528.218 us; speedup vs baseline: 1.0621x; 1.0230x over previous
//
#include <hip/hip_runtime.h>
#include <hip/hip_bf16.h>

#define NN 100000
#define NE 50000
#define NT 2000
#define DD 128
#define NEDGE 1600000
#define HID 512
#define OUTD 128
#define K1 (3*DD)   // 384: X layout [news | ent_agg | top_agg]
#define NBKT 391    // ceil(100000/256) buckets of 256 nodes

typedef __bf16 bf16x8 __attribute__((ext_vector_type(8)));
typedef __bf16 bf16x4 __attribute__((ext_vector_type(4)));
typedef float  f32x4  __attribute__((ext_vector_type(4)));

__device__ __forceinline__ __bf16 f2b(float f) {
    __hip_bfloat16 h = __float2bfloat16(f);
    union { __hip_bfloat16 h; __bf16 b; } u; u.h = h; return u.b;
}

__device__ __forceinline__ void gll16(const void* g, void* l) {
    __builtin_amdgcn_global_load_lds((const __attribute__((address_space(1))) void*)g,
                                     (__attribute__((address_space(3))) void*)l, 16, 0, 0);
}

__device__ __forceinline__ float ftanh(float x) {
    x = fminf(fmaxf(x, -15.f), 15.f);
    float t = __expf(2.f * x);
    return (t - 1.f) / (t + 1.f);
}

// ---- convert: ent/top tables -> bf16 tables; news -> bf16 into X cols 0..127 ----
__global__ void conv_feats(const float* __restrict__ entf, const float* __restrict__ topf,
                           const float* __restrict__ news,
                           __bf16* __restrict__ entb, __bf16* __restrict__ topb,
                           __bf16* __restrict__ X) {
    long i = ((long)blockIdx.x * 256 + threadIdx.x) * 4;
    const long NEL = (long)NE * DD;            // 6.4M
    const long NTL = (long)NT * DD;            // 0.256M
    if (i < NEL) {
        float4 v = *(const float4*)(entf + i);
        *(bf16x4*)(entb + i) = bf16x4{f2b(v.x), f2b(v.y), f2b(v.z), f2b(v.w)};
    } else if (i < NEL + NTL) {
        long j = i - NEL;
        float4 v = *(const float4*)(topf + j);
        *(bf16x4*)(topb + j) = bf16x4{f2b(v.x), f2b(v.y), f2b(v.z), f2b(v.w)};
    } else {
        long j = i - NEL - NTL;                // 0 .. 12.8M
        long row = j >> 7, col = j & 127;      // news [NN x 128], 4-aligned col
        float4 v = *(const float4*)(news + j);
        *(bf16x4*)(X + row * K1 + col) = bf16x4{f2b(v.x), f2b(v.y), f2b(v.z), f2b(v.w)};
    }
}

// ---- bucket histogram: LDS-local then one global atomic per (block,bucket) ----
__global__ __launch_bounds__(256) void hist_buckets(const int* __restrict__ er,
                                                    const int* __restrict__ tr,
                                                    int* __restrict__ bc_e,
                                                    int* __restrict__ bc_t) {
    __shared__ int lhe[NBKT], lht[NBKT];
    const int tid = threadIdx.x;
    for (int i = tid; i < NBKT; i += 256) { lhe[i] = 0; lht[i] = 0; }
    __syncthreads();
    const int base = blockIdx.x * 8192;
    #pragma unroll 4
    for (int k = 0; k < 32; k++) {
        int e = base + k * 256 + tid;
        if (e < NEDGE) {
            atomicAdd(&lhe[er[e] >> 8], 1);
            atomicAdd(&lht[tr[e] >> 8], 1);
        }
    }
    __syncthreads();
    for (int i = tid; i < NBKT; i += 256) {
        if (lhe[i]) atomicAdd(&bc_e[i], lhe[i]);
        if (lht[i]) atomicAdd(&bc_t[i], lht[i]);
    }
}

// ---- scan 391 bucket counts -> inclusive bc, exclusive cursors; offs[0]=0 ----
__global__ void scan_buckets(int* __restrict__ bc_e, int* __restrict__ bc_t,
                             int* __restrict__ cur_e, int* __restrict__ cur_t,
                             int* __restrict__ offs_e, int* __restrict__ offs_t) {
    int* bc  = blockIdx.y ? bc_t : bc_e;
    int* cur = blockIdx.y ? cur_t : cur_e;
    int* offs = blockIdx.y ? offs_t : offs_e;
    __shared__ int s[512];
    int i = threadIdx.x;
    s[i] = (i < NBKT) ? bc[i] : 0;
    __syncthreads();
    #pragma unroll
    for (int off = 1; off < 512; off <<= 1) {
        int v = (i >= off) ? s[i - off] : 0;
        __syncthreads();
        s[i] += v;
        __syncthreads();
    }
    if (i < NBKT) {
        bc[i] = s[i];
        cur[i] = i ? s[i - 1] : 0;
    }
    if (i == 0) offs[0] = 0;
}

// ---- partition edges into buckets ----
__global__ __launch_bounds__(256) void scatter_bucket(const int* __restrict__ er,
                                                      const int* __restrict__ ec,
                                                      const int* __restrict__ tr,
                                                      const int* __restrict__ tc,
                                                      int* __restrict__ cur_e,
                                                      int* __restrict__ cur_t,
                                                      int* __restrict__ be,
                                                      int* __restrict__ bt) {
    __shared__ int lhe[NBKT], lht[NBKT];   // counts, then local cursors
    __shared__ int lbe[NBKT], lbt[NBKT];   // reserved global bases
    const int tid = threadIdx.x;
    for (int i = tid; i < NBKT; i += 256) { lhe[i] = 0; lht[i] = 0; }
    __syncthreads();
    const int base = blockIdx.x * 4096;
    #pragma unroll 4
    for (int k = 0; k < 16; k++) {
        int e = base + k * 256 + tid;
        if (e < NEDGE) {
            atomicAdd(&lhe[er[e] >> 8], 1);
            atomicAdd(&lht[tr[e] >> 8], 1);
        }
    }
    __syncthreads();
    for (int i = tid; i < NBKT; i += 256) {
        int c = lhe[i];
        lbe[i] = c ? atomicAdd(&cur_e[i], c) : 0;
        lhe[i] = 0;
        c = lht[i];
        lbt[i] = c ? atomicAdd(&cur_t[i], c) : 0;
        lht[i] = 0;
    }
    __syncthreads();
    #pragma unroll 4
    for (int k = 0; k < 16; k++) {
        int e = base + k * 256 + tid;
        if (e < NEDGE) {
            int r = er[e];
            int b = r >> 8;
            int p = lbe[b] + atomicAdd(&lhe[b], 1);
            be[p] = ((r & 255) << 16) | ec[e];
            r = tr[e];
            b = r >> 8;
            p = lbt[b] + atomicAdd(&lht[b], 1);
            bt[p] = ((r & 255) << 16) | tc[e];
        }
    }
}

// ---- per-bucket exact CSR: local hist + scan -> offs + reorder cols ----
__global__ __launch_bounds__(256) void bucket_csr(const int* __restrict__ be,
                                                  const int* __restrict__ bt,
                                                  const int* __restrict__ bc_e,
                                                  const int* __restrict__ bc_t,
                                                  int* __restrict__ offs_e,
                                                  int* __restrict__ offs_t,
                                                  int* __restrict__ se,
                                                  int* __restrict__ st) {
    const int* buf = blockIdx.y ? bt : be;
    const int* bc  = blockIdx.y ? bc_t : bc_e;
    int* offs      = blockIdx.y ? offs_t : offs_e;
    int* sout      = blockIdx.y ? st : se;
    const int b = blockIdx.x;
    const int tid = threadIdx.x;
    const int start = b ? bc[b - 1] : 0;
    const int cnt = bc[b] - start;

    __shared__ int scn[256];
    __shared__ int lcur[256];
    scn[tid] = 0;
    __syncthreads();
    for (int i = tid; i < cnt; i += 256)
        atomicAdd(&scn[buf[start + i] >> 16], 1);
    __syncthreads();
    #pragma unroll
    for (int off = 1; off < 256; off <<= 1) {
        int v = (tid >= off) ? scn[tid - off] : 0;
        __syncthreads();
        scn[tid] += v;
        __syncthreads();
    }
    const int node = b * 256 + tid;
    if (node < NN) offs[node + 1] = start + scn[tid];
    lcur[tid] = start + (tid ? scn[tid - 1] : 0);
    __syncthreads();
    for (int i = tid; i < cnt; i += 256) {
        int v = buf[start + i];
        int p = atomicAdd(&lcur[v >> 16], 1);
        sout[p] = v & 0xFFFF;
    }
}

// ---- gather-aggregate (bf16 tables) -> X cols 128..383 ----
__global__ __launch_bounds__(256) void aggregate2(const __bf16* __restrict__ entb,
                                                  const __bf16* __restrict__ topb,
                                                  const int* __restrict__ offs_e,
                                                  const int* __restrict__ offs_t,
                                                  const int* __restrict__ se,
                                                  const int* __restrict__ st,
                                                  __bf16* __restrict__ X) {
    const int wave = threadIdx.x >> 6, lane = threadIdx.x & 63;
    const int node = blockIdx.x * 4 + wave;
    if (node >= NN) return;
    const int h = lane >> 4;        // 0..3: edge phase
    const int d = (lane & 15) * 8;  // dim group of 8

    float ea[8] = {0,0,0,0,0,0,0,0};
    float pa[8] = {0,0,0,0,0,0,0,0};

    const int s0 = offs_e[node], s1 = offs_e[node + 1];
    int i = s0 + h;
    for (; i + 12 < s1; i += 16) {
        int c0 = se[i], c1 = se[i + 4], c2 = se[i + 8], c3 = se[i + 12];
        bf16x8 v0 = *(const bf16x8*)(entb + (long)c0 * DD + d);
        bf16x8 v1 = *(const bf16x8*)(entb + (long)c1 * DD + d);
        bf16x8 v2 = *(const bf16x8*)(entb + (long)c2 * DD + d);
        bf16x8 v3 = *(const bf16x8*)(entb + (long)c3 * DD + d);
        #pragma unroll
        for (int j = 0; j < 8; j++)
            ea[j] += ((float)v0[j] + (float)v1[j]) + ((float)v2[j] + (float)v3[j]);
    }
    for (; i < s1; i += 4) {
        bf16x8 v = *(const bf16x8*)(entb + (long)se[i] * DD + d);
        #pragma unroll
        for (int j = 0; j < 8; j++) ea[j] += (float)v[j];
    }

    const int t0 = offs_t[node], t1 = offs_t[node + 1];
    i = t0 + h;
    for (; i + 12 < t1; i += 16) {
        int c0 = st[i], c1 = st[i + 4], c2 = st[i + 8], c3 = st[i + 12];
        bf16x8 v0 = *(const bf16x8*)(topb + (long)c0 * DD + d);
        bf16x8 v1 = *(const bf16x8*)(topb + (long)c1 * DD + d);
        bf16x8 v2 = *(const bf16x8*)(topb + (long)c2 * DD + d);
        bf16x8 v3 = *(const bf16x8*)(topb + (long)c3 * DD + d);
        #pragma unroll
        for (int j = 0; j < 8; j++)
            pa[j] += ((float)v0[j] + (float)v1[j]) + ((float)v2[j] + (float)v3[j]);
    }
    for (; i < t1; i += 4) {
        bf16x8 v = *(const bf16x8*)(topb + (long)st[i] * DD + d);
        #pragma unroll
        for (int j = 0; j < 8; j++) pa[j] += (float)v[j];
    }

    #pragma unroll
    for (int j = 0; j < 8; j++) {
        ea[j] += __shfl_xor(ea[j], 16, 64);
        ea[j] += __shfl_xor(ea[j], 32, 64);
        pa[j] += __shfl_xor(pa[j], 16, 64);
        pa[j] += __shfl_xor(pa[j], 32, 64);
    }

    const float ie = 1.0f / ((float)(s1 - s0) + 1e-8f);
    const float it = 1.0f / ((float)(t1 - t0) + 1e-8f);
    __bf16* xr = X + (long)node * K1;
    if (h == 1) {
        *(bf16x8*)(xr + DD + d) = bf16x8{f2b(ea[0]*ie), f2b(ea[1]*ie), f2b(ea[2]*ie), f2b(ea[3]*ie),
                                         f2b(ea[4]*ie), f2b(ea[5]*ie), f2b(ea[6]*ie), f2b(ea[7]*ie)};
    } else if (h == 2) {
        *(bf16x8*)(xr + 2*DD + d) = bf16x8{f2b(pa[0]*it), f2b(pa[1]*it), f2b(pa[2]*it), f2b(pa[3]*it),
                                           f2b(pa[4]*it), f2b(pa[5]*it), f2b(pa[6]*it), f2b(pa[7]*it)};
    }
}

// ---- W1 [384,512] -> W1T bf16 [512,384]; W2 [512,128] -> W2T bf16 [128,512] ----
__global__ void conv_w(const float* __restrict__ W1, const float* __restrict__ W2,
                       __bf16* __restrict__ W1T, __bf16* __restrict__ W2T) {
    int i = blockIdx.x * 256 + threadIdx.x;
    if (i < K1 * HID) {
        int k = i / HID, n = i % HID;
        W1T[n * K1 + k] = f2b(W1[i]);
    } else {
        int j = i - K1 * HID;
        if (j < HID * OUTD) {
            int k = j / OUTD, n = j % OUTD;
            W2T[n * HID + k] = f2b(W2[j]);
        }
    }
}

// ======== fused MLP: out = (tanh(X@W1T^T + b1)) @ W2T^T + b2 ========
// kt loop: 3-buffer depth-2 prefetch with COUNTED vmcnt + raw s_barrier
// (T3/T4): loads for phase t issued at t-2, never drained to 0 mid-loop.
// kk loop: simple 2-buffer __syncthreads rhythm (W2 tiles are L2-hot).

// stage a [128 x 32] bf16 tile (swizzled) from row-major bf16 src via global_load_lds
// issues exactly 2 gll16 instructions per thread
__device__ __forceinline__ void stage_tile(const __bf16* __restrict__ src, int ldK,
                                           int k0, int row0, int rowmax,
                                           __bf16* lds, int w, int lane) {
    #pragma unroll
    for (int half = 0; half < 2; half++) {
        int ss = w * 64 + half * 256 + lane;
        int r = ss >> 2;
        int sw = (r & 3) ^ ((r >> 2) & 3);
        int c = (ss & 3) ^ sw;
        int gr = row0 + r; if (gr >= rowmax) gr = rowmax - 1;
        gll16(src + (long)gr * ldK + k0 + c * 8,
              lds + (w * 64 + half * 256) * 8);
    }
}

// read fragment (logical row r, k-chunk q) from swizzled [128 x 32] tile
__device__ __forceinline__ bf16x8 frag(const __bf16* lds, int r, int q) {
    int sw = (r & 3) ^ ((r >> 2) & 3);
    return *(const bf16x8*)(lds + (r * 4 + (q ^ sw)) * 8);
}

// Hs [128 rows x 128 k] swizzled: chunk16 = kk*4+quad
__device__ __forceinline__ void hs_write(__bf16* Hs, int r, int c, __bf16 v) {
    int ch = c >> 3;
    int pch = ((((ch >> 2) ^ ((r >> 2) & 3)) << 2) | ((ch & 3) ^ (r & 3)));
    Hs[(r * 16 + pch) * 8 + (c & 7)] = v;
}
__device__ __forceinline__ bf16x8 hs_frag(const __bf16* Hs, int r, int kk, int q) {
    int pch = (((kk ^ ((r >> 2) & 3)) << 2) | (q ^ (r & 3)));
    return *(const bf16x8*)(Hs + (r * 16 + pch) * 8);
}

__global__ __launch_bounds__(256, 2) void mlp_fused(const __bf16* __restrict__ X,
                                                    const __bf16* __restrict__ W1T,
                                                    const float* __restrict__ b1,
                                                    const __bf16* __restrict__ W2T,
                                                    const float* __restrict__ b2,
                                                    float* __restrict__ out) {
    __shared__ __bf16 Xs[3][128 * 32];  // 3 x 8 KB
    __shared__ __bf16 Ws[3][128 * 32];  // 3 x 8 KB
    __shared__ __bf16 Hs[128 * 128];    // 32 KB  (total 80 KB -> 2 blocks/CU)
    const int bm = blockIdx.x * 128;
    const int t = threadIdx.x;
    const int lane = t & 63;
    const int w = t >> 6;
    const int quad = lane >> 4;
    const int l16 = lane & 15;
    const int wm = w >> 1, wn = w & 1;

    f32x4 oacc[4][4];
    #pragma unroll
    for (int i = 0; i < 4; i++)
        #pragma unroll
        for (int j = 0; j < 4; j++)
            #pragma unroll
            for (int r = 0; r < 4; r++) oacc[i][j][r] = 0.0f;

    // prologue: issue groups g0 (kt0) and g1 (kt1) for nc=0
    stage_tile(X,   K1, 0,  bm, NN,  Xs[0], w, lane);
    stage_tile(W1T, K1, 0,  0,  HID, Ws[0], w, lane);
    stage_tile(X,   K1, 32, bm, NN,  Xs[1], w, lane);
    stage_tile(W1T, K1, 32, 0,  HID, Ws[1], w, lane);

    for (int nc = 0; nc < 4; nc++) {
        f32x4 hacc[4][4];
        #pragma unroll
        for (int i = 0; i < 4; i++)
            #pragma unroll
            for (int j = 0; j < 4; j++)
                #pragma unroll
                for (int r = 0; r < 4; r++) hacc[i][j][r] = 0.0f;

        // ---- kt loop: counted-vmcnt 3-buffer pipeline ----
        #pragma unroll
        for (int kt = 0; kt < 12; kt++) {
            const int cb = kt % 3;
            // wait for this buffer's loads (issued at kt-2); keep newer group flying
            if (kt < 11) asm volatile("s_waitcnt vmcnt(4)" ::: "memory");
            else         asm volatile("s_waitcnt vmcnt(0)" ::: "memory");
            __builtin_amdgcn_s_barrier();
            bf16x8 af[4], bfr[4];
            #pragma unroll
            for (int i = 0; i < 4; i++) {
                af[i]  = frag(Xs[cb], wm * 64 + i * 16 + l16, quad);
                bfr[i] = frag(Ws[cb], wn * 64 + i * 16 + l16, quad);
            }
            if (kt < 10) {
                // stage kt+2 into buffer (kt+2)%3 (last read at kt-1; barrier-safe)
                const int nb = (kt + 2) % 3;
                stage_tile(X,   K1, (kt + 2) * 32, bm,       NN,  Xs[nb], w, lane);
                stage_tile(W1T, K1, (kt + 2) * 32, nc * 128, HID, Ws[nb], w, lane);
            }
            __builtin_amdgcn_s_setprio(1);
            #pragma unroll
            for (int i = 0; i < 4; i++)
                #pragma unroll
                for (int j = 0; j < 4; j++)
                    hacc[i][j] = __builtin_amdgcn_mfma_f32_16x16x32_bf16(af[i], bfr[j], hacc[i][j], 0, 0, 0);
            __builtin_amdgcn_s_setprio(0);
        }
        __syncthreads();   // all waves done reading Xs[2]/Ws[2]

        // stage W2 kk0 tile into Ws[2]; flies during the tanh pass
        stage_tile(W2T, HID, nc * 128, 0, OUTD, Ws[2], w, lane);

        // bias + tanh -> Hs (C/D layout: row=quad*4+reg, col=l16)
        #pragma unroll
        for (int j = 0; j < 4; j++) {
            const int col = wn * 64 + j * 16 + l16;
            const float bb = b1[nc * 128 + col];
            #pragma unroll
            for (int i = 0; i < 4; i++) {
                const int rbase = wm * 64 + i * 16 + quad * 4;
                #pragma unroll
                for (int r = 0; r < 4; r++)
                    hs_write(Hs, rbase + r, col, f2b(ftanh(hacc[i][j][r] + bb)));
            }
        }
        __syncthreads();   // Hs visible; W2 kk0 drained

        // ---- O += H_chunk @ W2T[:, nc*128..+128]^T ----
        for (int kk = 0; kk < 4; kk++) {
            __bf16* curb = (kk & 1) ? Xs[2] : Ws[2];
            __bf16* nxtb = (kk & 1) ? Ws[2] : Xs[2];
            if (kk < 3)
                stage_tile(W2T, HID, nc * 128 + (kk + 1) * 32, 0, OUTD, nxtb, w, lane);
            if (nc < 3) {
                if (kk == 2) {
                    stage_tile(X,   K1, 0, bm,             NN,  Xs[0], w, lane);
                    stage_tile(W1T, K1, 0, (nc + 1) * 128, HID, Ws[0], w, lane);
                } else if (kk == 3) {
                    stage_tile(X,   K1, 32, bm,             NN,  Xs[1], w, lane);
                    stage_tile(W1T, K1, 32, (nc + 1) * 128, HID, Ws[1], w, lane);
                }
            }
            bf16x8 af[4], bfr[4];
            #pragma unroll
            for (int i = 0; i < 4; i++) {
                af[i]  = hs_frag(Hs, wm * 64 + i * 16 + l16, kk, quad);
                bfr[i] = frag(curb, wn * 64 + i * 16 + l16, quad);
            }
            __builtin_amdgcn_s_setprio(1);
            #pragma unroll
            for (int i = 0; i < 4; i++)
                #pragma unroll
                for (int j = 0; j < 4; j++)
                    oacc[i][j] = __builtin_amdgcn_mfma_f32_16x16x32_bf16(af[i], bfr[j], oacc[i][j], 0, 0, 0);
            __builtin_amdgcn_s_setprio(0);
            __syncthreads();   // drains staged loads; separates buffer reuse
        }
    }

    // epilogue: out f32 [NN x 128]; j innermost -> full-line coverage fast
    float bb[4];
    #pragma unroll
    for (int j = 0; j < 4; j++) bb[j] = b2[wn * 64 + j * 16 + l16];
    #pragma unroll
    for (int i = 0; i < 4; i++) {
        #pragma unroll
        for (int r = 0; r < 4; r++) {
            const int gr = bm + wm * 64 + i * 16 + quad * 4 + r;
            if (gr < NN) {
                float* orow = out + (long)gr * OUTD + wn * 64 + l16;
                #pragma unroll
                for (int j = 0; j < 4; j++)
                    orow[j * 16] = oacc[i][j][r] + bb[j];
            }
        }
    }
}

extern "C" void kernel_launch(void* const* d_in, const int* in_sizes, int n_in,
                              void* d_out, int out_size, void* d_ws, size_t ws_size,
                              hipStream_t stream) {
    const float* news  = (const float*)d_in[0];
    const float* ent_f = (const float*)d_in[1];
    const float* top_f = (const float*)d_in[2];
    const int* ent_row = (const int*)d_in[3];
    const int* ent_col = (const int*)d_in[4];
    const int* top_row = (const int*)d_in[5];
    const int* top_col = (const int*)d_in[6];
    const float* W1 = (const float*)d_in[7];
    const float* b1 = (const float*)d_in[8];
    const float* W2 = (const float*)d_in[9];
    const float* b2 = (const float*)d_in[10];

    char* ws = (char*)d_ws;
    int* offs_e = (int*)(ws + 0);
    int* offs_t = (int*)(ws + 400016);
    int* bc_e   = (int*)(ws + 800032);
    int* bc_t   = (int*)(ws + 801596);
    int* cur_e  = (int*)(ws + 803160);
    int* cur_t  = (int*)(ws + 804724);
    int* be     = (int*)(ws + 806320);
    int* bt     = (int*)(ws + 7206320);
    int* se     = (int*)(ws + 13606320);
    int* st     = (int*)(ws + 20006320);
    __bf16* entb = (__bf16*)(ws + 26406336);
    __bf16* topb = (__bf16*)(ws + 39206336);
    __bf16* X   = (__bf16*)(ws + 102400000);
    __bf16* W1T = (__bf16*)(ws + 179200000);
    __bf16* W2T = (__bf16*)(ws + 179593216);

    hipMemsetAsync(ws + 800032, 0, 6256, stream);   // zero bc/cur arrays
    conv_w<<<1024, 256, 0, stream>>>(W1, W2, W1T, W2T);
    conv_feats<<<19000, 256, 0, stream>>>(ent_f, top_f, news, entb, topb, X);
    hist_buckets<<<196, 256, 0, stream>>>(ent_row, top_row, bc_e, bc_t);
    scan_buckets<<<dim3(1, 2), 512, 0, stream>>>(bc_e, bc_t, cur_e, cur_t, offs_e, offs_t);
    scatter_bucket<<<392, 256, 0, stream>>>(ent_row, ent_col, top_row, top_col,
                                            cur_e, cur_t, be, bt);
    bucket_csr<<<dim3(NBKT, 2), 256, 0, stream>>>(be, bt, bc_e, bc_t,
                                                  offs_e, offs_t, se, st);
    aggregate2<<<NN / 4, 256, 0, stream>>>(entb, topb, offs_e, offs_t, se, st, X);
    mlp_fused<<<782, 256, 0, stream>>>(X, W1T, b1, W2T, b2, (float*)d_out);
}